// Round 2
// baseline (158.741 us; speedup 1.0000x reference)
//
#include <hip/hip_runtime.h>

#define IMG_H 512
#define IMG_W 512
#define N_IMG 32
#define ROWS  4                    // output rows per wave-band
#define BANDS (IMG_H / ROWS)       // 128 bands per image
#define ITERS (ROWS + 8)           // 12 row-slides per band
#define NPIX  (32.0f * 512.0f * 512.0f)

// Load 8 consecutive cols of I and normalized T from row r (zeros if r out of range).
__device__ __forceinline__ void load8(const float* __restrict__ ip,
                                      const float* __restrict__ tp,
                                      int r, int c0, float* I, float* T) {
    if (r >= 0 && r < IMG_H) {
        const float* irow = ip + (ptrdiff_t)r * IMG_W + c0;
        const float* trow = tp + (ptrdiff_t)r * IMG_W + c0;
        float4 a = *(const float4*)(irow);
        float4 b = *(const float4*)(irow + 4);
        float4 c = *(const float4*)(trow);
        float4 d = *(const float4*)(trow + 4);
        I[0]=a.x; I[1]=a.y; I[2]=a.z; I[3]=a.w;
        I[4]=b.x; I[5]=b.y; I[6]=b.z; I[7]=b.w;
        T[0]=fmaf(c.x,0.5f,0.5f); T[1]=fmaf(c.y,0.5f,0.5f);
        T[2]=fmaf(c.z,0.5f,0.5f); T[3]=fmaf(c.w,0.5f,0.5f);
        T[4]=fmaf(d.x,0.5f,0.5f); T[5]=fmaf(d.y,0.5f,0.5f);
        T[6]=fmaf(d.z,0.5f,0.5f); T[7]=fmaf(d.w,0.5f,0.5f);
    } else {
        #pragma unroll
        for (int j = 0; j < 8; ++j) { I[j] = 0.0f; T[j] = 0.0f; }
    }
}

// Halo exchange for one array: L[k] = lane-1's o[4+k], R[k] = lane+1's o[k].
__device__ __forceinline__ void halo(const float* o, float* L, float* R, bool nf, bool nl) {
    #pragma unroll
    for (int k = 0; k < 4; ++k) {
        float l = __shfl_up(o[4 + k], 1, 64);
        float r = __shfl_down(o[k],   1, 64);
        L[k] = nf ? l : 0.0f;
        R[k] = nl ? r : 0.0f;
    }
}

__device__ __forceinline__ float cc_of(float sI, float sT, float sII, float sTT, float sIT) {
    const float inv81 = 1.0f / 81.0f;
    float u     = sI * inv81;
    float w     = sT * inv81;
    float cross = fmaf(-u, sT, sIT);
    float iv    = fmaf(-u, sI, sII);
    float tv    = fmaf(-w, sT, sTT);
    float den   = fmaf(tv, iv, 1e-5f);
    return cross * cross * __builtin_amdgcn_rcpf(den);
}

__global__ __launch_bounds__(256, 3)
void cc_loss_kernel(const float* __restrict__ in, const float* __restrict__ tg,
                    float* __restrict__ out) {
    __shared__ float red[4];

    const int t    = threadIdx.x;
    const int w    = t >> 6;
    const int lane = t & 63;

    const int gband = blockIdx.x * 4 + w;      // 0..4095
    const int b     = gband >> 7;              // image (128 bands each)
    const int band  = gband & (BANDS - 1);
    const int r0    = band * ROWS;
    const size_t base = (size_t)b * (IMG_H * IMG_W);
    const float* ip = in + base;
    const float* tp = tg + base;
    const int c0    = lane * 8;                // own image cols c0..c0+7
    const bool nf   = (lane != 0);
    const bool nl   = (lane != 63);

    float vI[8] = {}, vT[8] = {}, vII[8] = {}, vTT[8] = {}, vIT[8] = {};
    float acc = 0.0f;

    // depth-2 double buffer, slots selected by compile-time (it&1) after full unroll
    float bLI[2][8], bLT[2][8], bQI[2][8], bQT[2][8];
    load8(ip, tp, r0 - 4, c0, bLI[0], bLT[0]);   // lead for it=0
    load8(ip, tp, r0 - 3, c0, bLI[1], bLT[1]);   // lead for it=1
    #pragma unroll
    for (int j = 0; j < 8; ++j) {
        bQI[0][j] = 0.0f; bQT[0][j] = 0.0f;
        bQI[1][j] = 0.0f; bQT[1][j] = 0.0f;
    }

    #pragma unroll
    for (int it = 0; it < ITERS; ++it) {
        const int s = it & 1;

        // copy-out (pure renames after unroll), then refill slot for it+2
        float cLI[8], cLT[8], cQI[8], cQT[8];
        #pragma unroll
        for (int j = 0; j < 8; ++j) {
            cLI[j] = bLI[s][j]; cLT[j] = bLT[s][j];
            cQI[j] = bQI[s][j]; cQT[j] = bQT[s][j];
        }

        if (it + 2 < ITERS) {
            load8(ip, tp, r0 - 2 + it, c0, bLI[s], bLT[s]);              // lead(it+2)
            load8(ip, tp, (it >= 7) ? (r0 + it - 11) : -1, c0,
                  bQI[s], bQT[s]);                                       // trail(it+2)
        }

        // ---- vertical slide: 8 own cols, 5 arrays ----
        #pragma unroll
        for (int j = 0; j < 8; ++j) {
            float dI = cLI[j] - cQI[j], aI = cLI[j] + cQI[j];
            float dT = cLT[j] - cQT[j], aT = cLT[j] + cQT[j];
            vI[j]  += dI;
            vT[j]  += dT;
            vII[j]  = fmaf(dI, aI, vII[j]);
            vTT[j]  = fmaf(dT, aT, vTT[j]);
            float m = cQI[j] * cQT[j];
            vIT[j]  = fmaf(cLI[j], cLT[j], vIT[j] - m);
        }

        // ---- H phase: shuffle halos + fused running sums (low liveness) ----
        if (it >= 8) {
            float L0[4], R0[4], L1[4], R1[4], L2[4], R2[4],
                  L3[4], R3[4], L4[4], R4[4];
            halo(vI,  L0, R0, nf, nl);
            halo(vT,  L1, R1, nf, nl);
            halo(vII, L2, R2, nf, nl);
            halo(vTT, L3, R3, nf, nl);
            halo(vIT, L4, R4, nf, nl);

            float s0 = ((L0[0]+L0[1])+(L0[2]+L0[3])) + ((vI[0] +vI[1]) +(vI[2] +vI[3])) + vI[4];
            float s1 = ((L1[0]+L1[1])+(L1[2]+L1[3])) + ((vT[0] +vT[1]) +(vT[2] +vT[3])) + vT[4];
            float s2 = ((L2[0]+L2[1])+(L2[2]+L2[3])) + ((vII[0]+vII[1])+(vII[2]+vII[3])) + vII[4];
            float s3 = ((L3[0]+L3[1])+(L3[2]+L3[3])) + ((vTT[0]+vTT[1])+(vTT[2]+vTT[3])) + vTT[4];
            float s4 = ((L4[0]+L4[1])+(L4[2]+L4[3])) + ((vIT[0]+vIT[1])+(vIT[2]+vIT[3])) + vIT[4];
            acc += cc_of(s0, s1, s2, s3, s4);

            #define HSTEP(a0,a1,a2,a3,a4) \
                s0 += (a0); s1 += (a1); s2 += (a2); s3 += (a3); s4 += (a4); \
                acc += cc_of(s0, s1, s2, s3, s4);

            HSTEP(vI[5]-L0[0], vT[5]-L1[0], vII[5]-L2[0], vTT[5]-L3[0], vIT[5]-L4[0])  // j=1
            HSTEP(vI[6]-L0[1], vT[6]-L1[1], vII[6]-L2[1], vTT[6]-L3[1], vIT[6]-L4[1])  // j=2
            HSTEP(vI[7]-L0[2], vT[7]-L1[2], vII[7]-L2[2], vTT[7]-L3[2], vIT[7]-L4[2])  // j=3
            HSTEP(R0[0]-L0[3], R1[0]-L1[3], R2[0]-L2[3], R3[0]-L3[3], R4[0]-L4[3])     // j=4
            HSTEP(R0[1]-vI[0], R1[1]-vT[0], R2[1]-vII[0], R3[1]-vTT[0], R4[1]-vIT[0])  // j=5
            HSTEP(R0[2]-vI[1], R1[2]-vT[1], R2[2]-vII[1], R3[2]-vTT[1], R4[2]-vIT[1])  // j=6
            HSTEP(R0[3]-vI[2], R1[3]-vT[2], R2[3]-vII[2], R3[3]-vTT[2], R4[3]-vIT[2])  // j=7
            #undef HSTEP
        }
    }

    // ---- reduction: wave shuffle, one barrier per block, one atomic ----
    #pragma unroll
    for (int off = 32; off > 0; off >>= 1) acc += __shfl_down(acc, off, 64);
    if (lane == 0) red[w] = acc;
    __syncthreads();
    if (t == 0)
        atomicAdd(out, (red[0] + red[1] + red[2] + red[3]) * (-1.0f / NPIX));
}

extern "C" void kernel_launch(void* const* d_in, const int* in_sizes, int n_in,
                              void* d_out, int out_size, void* d_ws, size_t ws_size,
                              hipStream_t stream) {
    const float* in = (const float*)d_in[0];
    const float* tg = (const float*)d_in[1];
    float* out = (float*)d_out;

    hipMemsetAsync(out, 0, sizeof(float), stream);
    dim3 grid(N_IMG * BANDS / 4);              // 1024 blocks x 4 wave-bands
    cc_loss_kernel<<<grid, 256, 0, stream>>>(in, tg, out);
}

// Round 3
// 139.864 us; speedup vs baseline: 1.1350x; 1.1350x over previous
//
#include <hip/hip_runtime.h>

#define IMG_H 512
#define IMG_W 512
#define N_IMG 32
#define ROWS  8                    // output rows per wave-band
#define BANDS (IMG_H / ROWS)       // 64 bands per image
#define NPIX  (32.0f * 512.0f * 512.0f)

// ---- DPP lane shifts: wave_shr:1 (lane i <- lane i-1, lane0 <- 0),
//      wave_shl:1 (lane i <- lane i+1, lane63 <- 0). bound_ctrl zero-fill
//      implements the image-edge zero padding for free (no cndmask).
__device__ __forceinline__ float dpp_left(float x) {
    return __int_as_float(__builtin_amdgcn_update_dpp(
        0, __float_as_int(x), 0x138, 0xf, 0xf, true));   // wave_shr:1
}
__device__ __forceinline__ float dpp_right(float x) {
    return __int_as_float(__builtin_amdgcn_update_dpp(
        0, __float_as_int(x), 0x130, 0xf, 0xf, true));   // wave_shl:1
}

// Raw loads (no normalize here -> no vmcnt-forcing ALU at the prefetch site).
// Out-of-range rows: I = 0, T_raw = -1 so fmaf(-1,0.5,0.5) = 0 at consumption.
__device__ __forceinline__ void load8raw(const float* __restrict__ ip,
                                         const float* __restrict__ tp,
                                         int r, int c0, float* I, float* T) {
    if (r >= 0 && r < IMG_H) {
        const float* irow = ip + (ptrdiff_t)r * IMG_W + c0;
        const float* trow = tp + (ptrdiff_t)r * IMG_W + c0;
        float4 a = *(const float4*)(irow);
        float4 b = *(const float4*)(irow + 4);
        float4 c = *(const float4*)(trow);
        float4 d = *(const float4*)(trow + 4);
        I[0]=a.x; I[1]=a.y; I[2]=a.z; I[3]=a.w;
        I[4]=b.x; I[5]=b.y; I[6]=b.z; I[7]=b.w;
        T[0]=c.x; T[1]=c.y; T[2]=c.z; T[3]=c.w;
        T[4]=d.x; T[5]=d.y; T[6]=d.z; T[7]=d.w;
    } else {
        #pragma unroll
        for (int j = 0; j < 8; ++j) { I[j] = 0.0f; T[j] = -1.0f; }
    }
}

// Vertical slide, ramp phase (no trailing row yet).
__device__ __forceinline__ void slide_lead(const float* LI, const float* LTr,
                                           float* vI, float* vT, float* vII,
                                           float* vTT, float* vIT) {
    #pragma unroll
    for (int j = 0; j < 8; ++j) {
        float li = LI[j];
        float lt = fmaf(LTr[j], 0.5f, 0.5f);
        vI[j]  += li;
        vT[j]  += lt;
        vII[j]  = fmaf(li, li, vII[j]);
        vTT[j]  = fmaf(lt, lt, vTT[j]);
        vIT[j]  = fmaf(li, lt, vIT[j]);
    }
}

// Vertical slide, steady state (add leading row, subtract trailing row).
__device__ __forceinline__ void slide_full(const float* LI, const float* LTr,
                                           const float* QI, const float* QTr,
                                           float* vI, float* vT, float* vII,
                                           float* vTT, float* vIT) {
    #pragma unroll
    for (int j = 0; j < 8; ++j) {
        float li = LI[j], qi = QI[j];
        float lt = fmaf(LTr[j], 0.5f, 0.5f);
        float qt = fmaf(QTr[j], 0.5f, 0.5f);
        float dI = li - qi, aI = li + qi;
        float dT = lt - qt, aT = lt + qt;
        vI[j]  += dI;
        vT[j]  += dT;
        vII[j]  = fmaf(dI, aI, vII[j]);
        vTT[j]  = fmaf(dT, aT, vTT[j]);
        vIT[j]  = fmaf(li, lt, vIT[j] - qi * qt);
    }
}

__device__ __forceinline__ float cc_of(float sI, float sT, float sII, float sTT, float sIT) {
    const float inv81 = 1.0f / 81.0f;
    float u     = sI * inv81;
    float w     = sT * inv81;
    float cross = fmaf(-u, sT, sIT);
    float iv    = fmaf(-u, sI, sII);
    float tv    = fmaf(-w, sT, sTT);
    float den   = fmaf(tv, iv, 1e-5f);
    return cross * cross * __builtin_amdgcn_rcpf(den);
}

// Horizontal 9-tap sums + cc for 8 own cols; halos via DPP shifts.
__device__ __forceinline__ float hphase(const float* vI, const float* vT,
                                        const float* vII, const float* vTT,
                                        const float* vIT) {
    float L0[4],R0[4],L1[4],R1[4],L2[4],R2[4],L3[4],R3[4],L4[4],R4[4];
    #pragma unroll
    for (int k = 0; k < 4; ++k) {
        L0[k] = dpp_left (vI [4+k]);  R0[k] = dpp_right(vI [k]);
        L1[k] = dpp_left (vT [4+k]);  R1[k] = dpp_right(vT [k]);
        L2[k] = dpp_left (vII[4+k]);  R2[k] = dpp_right(vII[k]);
        L3[k] = dpp_left (vTT[4+k]);  R3[k] = dpp_right(vTT[k]);
        L4[k] = dpp_left (vIT[4+k]);  R4[k] = dpp_right(vIT[k]);
    }
    float s0 = ((L0[0]+L0[1])+(L0[2]+L0[3])) + ((vI [0]+vI [1])+(vI [2]+vI [3])) + vI [4];
    float s1 = ((L1[0]+L1[1])+(L1[2]+L1[3])) + ((vT [0]+vT [1])+(vT [2]+vT [3])) + vT [4];
    float s2 = ((L2[0]+L2[1])+(L2[2]+L2[3])) + ((vII[0]+vII[1])+(vII[2]+vII[3])) + vII[4];
    float s3 = ((L3[0]+L3[1])+(L3[2]+L3[3])) + ((vTT[0]+vTT[1])+(vTT[2]+vTT[3])) + vTT[4];
    float s4 = ((L4[0]+L4[1])+(L4[2]+L4[3])) + ((vIT[0]+vIT[1])+(vIT[2]+vIT[3])) + vIT[4];
    float part = cc_of(s0, s1, s2, s3, s4);

    #define HSTEP(a0,a1,a2,a3,a4) \
        s0 += (a0); s1 += (a1); s2 += (a2); s3 += (a3); s4 += (a4); \
        part += cc_of(s0, s1, s2, s3, s4);

    HSTEP(vI[5]-L0[0], vT[5]-L1[0], vII[5]-L2[0], vTT[5]-L3[0], vIT[5]-L4[0])  // j=1
    HSTEP(vI[6]-L0[1], vT[6]-L1[1], vII[6]-L2[1], vTT[6]-L3[1], vIT[6]-L4[1])  // j=2
    HSTEP(vI[7]-L0[2], vT[7]-L1[2], vII[7]-L2[2], vTT[7]-L3[2], vIT[7]-L4[2])  // j=3
    HSTEP(R0[0]-L0[3], R1[0]-L1[3], R2[0]-L2[3], R3[0]-L3[3], R4[0]-L4[3])     // j=4
    HSTEP(R0[1]-vI[0], R1[1]-vT[0], R2[1]-vII[0], R3[1]-vTT[0], R4[1]-vIT[0])  // j=5
    HSTEP(R0[2]-vI[1], R1[2]-vT[1], R2[2]-vII[1], R3[2]-vTT[1], R4[2]-vIT[1])  // j=6
    HSTEP(R0[3]-vI[2], R1[3]-vT[2], R2[3]-vII[2], R3[3]-vTT[2], R4[3]-vIT[2])  // j=7
    #undef HSTEP
    return part;
}

__global__ __launch_bounds__(256)
void cc_loss_kernel(const float* __restrict__ in, const float* __restrict__ tg,
                    float* __restrict__ out) {
    __shared__ float red[4];

    const int t    = threadIdx.x;
    const int w    = t >> 6;
    const int lane = t & 63;

    const int gband = blockIdx.x * 4 + w;      // 0..2047
    const int b     = gband >> 6;              // image (64 bands each)
    const int band  = gband & 63;
    const int r0    = band * ROWS;
    const size_t base = (size_t)b * (IMG_H * IMG_W);
    const float* ip = in + base;
    const float* tp = tg + base;
    const int c0    = lane * 8;                // own image cols c0..c0+7

    float vI[8] = {}, vT[8] = {}, vII[8] = {}, vTT[8] = {}, vIT[8] = {};
    float acc = 0.0f;

    // Named ping-pong buffers: A serves even iters, B serves odd iters.
    // No index-by-parity arrays, no rotate copies -> cannot spill-collapse.
    float ALI[8], ALT[8], AQI[8], AQT[8];
    float BLI[8], BLT[8], BQI[8], BQT[8];

    load8raw(ip, tp, r0 - 4, c0, ALI, ALT);              // lead(0)

    // ---- ramp: iters k = 0..7 (no trailing row, no H phase) ----
    #pragma unroll
    for (int p = 0; p < 4; ++p) {
        const int k = 2 * p;
        load8raw(ip, tp, r0 - 3 + k, c0, BLI, BLT);      // lead(k+1)
        slide_lead(ALI, ALT, vI, vT, vII, vTT, vIT);     // consume iter k
        load8raw(ip, tp, r0 - 2 + k, c0, ALI, ALT);      // lead(k+2)
        slide_lead(BLI, BLT, vI, vT, vII, vTT, vIT);     // consume iter k+1
    }

    // ---- hot: iters k = 8..15 (H phase every iter; trail from k=9) ----
    #pragma unroll
    for (int p = 0; p < 4; ++p) {
        const int k = 8 + 2 * p;
        // prefetch for iter k+1 (odd: trailing row active, row r0+(k+1)-13)
        load8raw(ip, tp, r0 - 3 + k,  c0, BLI, BLT);     // lead(k+1)
        load8raw(ip, tp, r0 + k - 12, c0, BQI, BQT);     // trail(k+1)

        if (p == 0) slide_lead(ALI, ALT, vI, vT, vII, vTT, vIT);           // iter 8
        else        slide_full(ALI, ALT, AQI, AQT, vI, vT, vII, vTT, vIT); // iters 10,12,14
        acc += hphase(vI, vT, vII, vTT, vIT);

        if (p < 3) {
            // prefetch for iter k+2 (even: trail row r0+(k+2)-13)
            load8raw(ip, tp, r0 - 2 + k,  c0, ALI, ALT); // lead(k+2)
            load8raw(ip, tp, r0 + k - 11, c0, AQI, AQT); // trail(k+2)
        }
        slide_full(BLI, BLT, BQI, BQT, vI, vT, vII, vTT, vIT);             // iter k+1
        acc += hphase(vI, vT, vII, vTT, vIT);
    }

    // ---- reduction: wave shuffle, one barrier per block, one atomic ----
    #pragma unroll
    for (int off = 32; off > 0; off >>= 1) acc += __shfl_down(acc, off, 64);
    if (lane == 0) red[w] = acc;
    __syncthreads();
    if (t == 0)
        atomicAdd(out, (red[0] + red[1] + red[2] + red[3]) * (-1.0f / NPIX));
}

extern "C" void kernel_launch(void* const* d_in, const int* in_sizes, int n_in,
                              void* d_out, int out_size, void* d_ws, size_t ws_size,
                              hipStream_t stream) {
    const float* in = (const float*)d_in[0];
    const float* tg = (const float*)d_in[1];
    float* out = (float*)d_out;

    hipMemsetAsync(out, 0, sizeof(float), stream);
    dim3 grid(N_IMG * BANDS / 4);              // 512 blocks x 4 wave-bands
    cc_loss_kernel<<<grid, 256, 0, stream>>>(in, tg, out);
}

// Round 4
// 106.972 us; speedup vs baseline: 1.4839x; 1.3075x over previous
//
#include <hip/hip_runtime.h>

#define IMG_H 512
#define IMG_W 512
#define N_IMG 32
#define ROWS  8                    // output rows per wave-band
#define BANDS (IMG_H / ROWS)       // 64 bands per image
#define NPIX  (32.0f * 512.0f * 512.0f)

// ---- DPP lane shifts (verified R3): wave_shr:1 / wave_shl:1 with
//      bound_ctrl zero-fill = free image-edge zero padding.
__device__ __forceinline__ float dpp_left(float x) {
    return __int_as_float(__builtin_amdgcn_update_dpp(
        0, __float_as_int(x), 0x138, 0xf, 0xf, true));   // wave_shr:1
}
__device__ __forceinline__ float dpp_right(float x) {
    return __int_as_float(__builtin_amdgcn_update_dpp(
        0, __float_as_int(x), 0x130, 0xf, 0xf, true));   // wave_shl:1
}

// Raw loads; out-of-range rows: I = 0, T_raw = -1 (normalizes to 0).
__device__ __forceinline__ void load8raw(const float* __restrict__ ip,
                                         const float* __restrict__ tp,
                                         int r, int c0, float* I, float* T) {
    if (r >= 0 && r < IMG_H) {
        const float* irow = ip + (ptrdiff_t)r * IMG_W + c0;
        const float* trow = tp + (ptrdiff_t)r * IMG_W + c0;
        float4 a = *(const float4*)(irow);
        float4 b = *(const float4*)(irow + 4);
        float4 c = *(const float4*)(trow);
        float4 d = *(const float4*)(trow + 4);
        I[0]=a.x; I[1]=a.y; I[2]=a.z; I[3]=a.w;
        I[4]=b.x; I[5]=b.y; I[6]=b.z; I[7]=b.w;
        T[0]=c.x; T[1]=c.y; T[2]=c.z; T[3]=c.w;
        T[4]=d.x; T[5]=d.y; T[6]=d.z; T[7]=d.w;
    } else {
        #pragma unroll
        for (int j = 0; j < 8; ++j) { I[j] = 0.0f; T[j] = -1.0f; }
    }
}

__device__ __forceinline__ void slide_lead(const float* LI, const float* LTr,
                                           float* vI, float* vT, float* vII,
                                           float* vTT, float* vIT) {
    #pragma unroll
    for (int j = 0; j < 8; ++j) {
        float li = LI[j];
        float lt = fmaf(LTr[j], 0.5f, 0.5f);
        vI[j]  += li;
        vT[j]  += lt;
        vII[j]  = fmaf(li, li, vII[j]);
        vTT[j]  = fmaf(lt, lt, vTT[j]);
        vIT[j]  = fmaf(li, lt, vIT[j]);
    }
}

__device__ __forceinline__ void slide_full(const float* LI, const float* LTr,
                                           const float* QI, const float* QTr,
                                           float* vI, float* vT, float* vII,
                                           float* vTT, float* vIT) {
    #pragma unroll
    for (int j = 0; j < 8; ++j) {
        float li = LI[j], qi = QI[j];
        float lt = fmaf(LTr[j], 0.5f, 0.5f);
        float qt = fmaf(QTr[j], 0.5f, 0.5f);
        float dI = li - qi, aI = li + qi;
        float dT = lt - qt, aT = lt + qt;
        vI[j]  += dI;
        vT[j]  += dT;
        vII[j]  = fmaf(dI, aI, vII[j]);
        vTT[j]  = fmaf(dT, aT, vTT[j]);
        vIT[j]  = fmaf(li, lt, vIT[j] - qi * qt);
    }
}

__device__ __forceinline__ float cc_of(float sI, float sT, float sII, float sTT, float sIT) {
    const float inv81 = 1.0f / 81.0f;
    float u     = sI * inv81;
    float w     = sT * inv81;
    float cross = fmaf(-u, sT, sIT);
    float iv    = fmaf(-u, sI, sII);
    float tv    = fmaf(-w, sT, sTT);
    float den   = fmaf(tv, iv, 1e-5f);
    return cross * cross * __builtin_amdgcn_rcpf(den);
}

// Horizontal 9-tap sums + cc for 8 own cols; halos via DPP (verified R3).
__device__ __forceinline__ float hphase(const float* vI, const float* vT,
                                        const float* vII, const float* vTT,
                                        const float* vIT) {
    float L0[4],R0[4],L1[4],R1[4],L2[4],R2[4],L3[4],R3[4],L4[4],R4[4];
    #pragma unroll
    for (int k = 0; k < 4; ++k) {
        L0[k] = dpp_left (vI [4+k]);  R0[k] = dpp_right(vI [k]);
        L1[k] = dpp_left (vT [4+k]);  R1[k] = dpp_right(vT [k]);
        L2[k] = dpp_left (vII[4+k]);  R2[k] = dpp_right(vII[k]);
        L3[k] = dpp_left (vTT[4+k]);  R3[k] = dpp_right(vTT[k]);
        L4[k] = dpp_left (vIT[4+k]);  R4[k] = dpp_right(vIT[k]);
    }
    float s0 = ((L0[0]+L0[1])+(L0[2]+L0[3])) + ((vI [0]+vI [1])+(vI [2]+vI [3])) + vI [4];
    float s1 = ((L1[0]+L1[1])+(L1[2]+L1[3])) + ((vT [0]+vT [1])+(vT [2]+vT [3])) + vT [4];
    float s2 = ((L2[0]+L2[1])+(L2[2]+L2[3])) + ((vII[0]+vII[1])+(vII[2]+vII[3])) + vII[4];
    float s3 = ((L3[0]+L3[1])+(L3[2]+L3[3])) + ((vTT[0]+vTT[1])+(vTT[2]+vTT[3])) + vTT[4];
    float s4 = ((L4[0]+L4[1])+(L4[2]+L4[3])) + ((vIT[0]+vIT[1])+(vIT[2]+vIT[3])) + vIT[4];
    float part = cc_of(s0, s1, s2, s3, s4);

    #define HSTEP(a0,a1,a2,a3,a4) \
        s0 += (a0); s1 += (a1); s2 += (a2); s3 += (a3); s4 += (a4); \
        part += cc_of(s0, s1, s2, s3, s4);

    HSTEP(vI[5]-L0[0], vT[5]-L1[0], vII[5]-L2[0], vTT[5]-L3[0], vIT[5]-L4[0])  // j=1
    HSTEP(vI[6]-L0[1], vT[6]-L1[1], vII[6]-L2[1], vTT[6]-L3[1], vIT[6]-L4[1])  // j=2
    HSTEP(vI[7]-L0[2], vT[7]-L1[2], vII[7]-L2[2], vTT[7]-L3[2], vIT[7]-L4[2])  // j=3
    HSTEP(R0[0]-L0[3], R1[0]-L1[3], R2[0]-L2[3], R3[0]-L3[3], R4[0]-L4[3])     // j=4
    HSTEP(R0[1]-vI[0], R1[1]-vT[0], R2[1]-vII[0], R3[1]-vTT[0], R4[1]-vIT[0])  // j=5
    HSTEP(R0[2]-vI[1], R1[2]-vT[1], R2[2]-vII[1], R3[2]-vTT[1], R4[2]-vIT[1])  // j=6
    HSTEP(R0[3]-vI[2], R1[3]-vT[2], R2[3]-vII[2], R3[3]-vTT[2], R4[3]-vIT[2])  // j=7
    #undef HSTEP
    return part;
}

__global__ __launch_bounds__(256)
void cc_loss_kernel(const float* __restrict__ in, const float* __restrict__ tg,
                    float* __restrict__ out) {
    __shared__ float red[4];

    const int t    = threadIdx.x;
    const int w    = t >> 6;
    const int lane = t & 63;

    // XCD-chunked swizzle: HW round-robins blockIdx over 8 XCDs; remap so
    // each XCD owns 64 consecutive blocks = 4 whole images -> halo rows
    // shared by adjacent bands hit the same XCD's L2.
    const int bid  = blockIdx.x;                       // 0..511
    const int bs   = (bid & 7) * 64 + (bid >> 3);      // bijective (512 % 8 == 0)

    const int gband = bs * 4 + w;              // 0..2047
    const int b     = gband >> 6;              // image (64 bands each)
    const int band  = gband & 63;
    const int r0    = band * ROWS;
    const size_t base = (size_t)b * (IMG_H * IMG_W);
    const float* ip = in + base;
    const float* tp = tg + base;
    const int c0    = lane * 8;                // own image cols c0..c0+7

    float vI[8] = {}, vT[8] = {}, vII[8] = {}, vTT[8] = {}, vIT[8] = {};
    float acc = 0.0f;

    // Named buffers only (no indexable arrays -> no spill-collapse).
    // A/B: hot-loop ping-pong (lead + trail). C/D: ramp-only lead buffers.
    float ALI[8], ALT[8], AQI[8], AQT[8];
    float BLI[8], BLT[8], BQI[8], BQT[8];
    float CLI[8], CLT[8], DLI[8], DLT[8];

    // ---- ramp: add window rows r0-4 .. r0+3 (iters 0..7), depth-4 pipeline ----
    load8raw(ip, tp, r0 - 4, c0, ALI, ALT);
    load8raw(ip, tp, r0 - 3, c0, BLI, BLT);
    load8raw(ip, tp, r0 - 2, c0, CLI, CLT);
    load8raw(ip, tp, r0 - 1, c0, DLI, DLT);

    slide_lead(ALI, ALT, vI, vT, vII, vTT, vIT);
    load8raw(ip, tp, r0 + 0, c0, ALI, ALT);
    slide_lead(BLI, BLT, vI, vT, vII, vTT, vIT);
    load8raw(ip, tp, r0 + 1, c0, BLI, BLT);
    slide_lead(CLI, CLT, vI, vT, vII, vTT, vIT);
    load8raw(ip, tp, r0 + 2, c0, CLI, CLT);
    slide_lead(DLI, DLT, vI, vT, vII, vTT, vIT);
    load8raw(ip, tp, r0 + 3, c0, DLI, DLT);

    slide_lead(ALI, ALT, vI, vT, vII, vTT, vIT);
    load8raw(ip, tp, r0 + 4, c0, ALI, ALT);            // lead(iter 8)
    slide_lead(BLI, BLT, vI, vT, vII, vTT, vIT);
    load8raw(ip, tp, r0 + 5, c0, BLI, BLT);            // lead(iter 9)
    load8raw(ip, tp, r0 - 4, c0, BQI, BQT);            // trail(iter 9)
    slide_lead(CLI, CLT, vI, vT, vII, vTT, vIT);
    slide_lead(DLI, DLT, vI, vT, vII, vTT, vIT);

    // ---- hot: iters k = 8..15, rolling ping-pong, prefetch distance = 1 pass ----
    #pragma unroll 1
    for (int p = 0; p < 4; ++p) {
        const int k = 8 + 2 * p;

        // iter k (A): window now r0-4+k-8 .. r0+k-4
        if (p == 0) slide_lead(ALI, ALT, vI, vT, vII, vTT, vIT);
        else        slide_full(ALI, ALT, AQI, AQT, vI, vT, vII, vTT, vIT);
        if (p < 3) {
            load8raw(ip, tp, r0 + k - 2,  c0, ALI, ALT);   // lead(k+2)
            load8raw(ip, tp, r0 + k - 11, c0, AQI, AQT);   // trail(k+2)
        }
        acc += hphase(vI, vT, vII, vTT, vIT);

        // iter k+1 (B)
        slide_full(BLI, BLT, BQI, BQT, vI, vT, vII, vTT, vIT);
        if (p < 3) {
            load8raw(ip, tp, r0 + k - 1,  c0, BLI, BLT);   // lead(k+3)
            load8raw(ip, tp, r0 + k - 10, c0, BQI, BQT);   // trail(k+3)
        }
        acc += hphase(vI, vT, vII, vTT, vIT);
    }

    // ---- reduction: wave shuffle, one barrier per block, one atomic ----
    #pragma unroll
    for (int off = 32; off > 0; off >>= 1) acc += __shfl_down(acc, off, 64);
    if (lane == 0) red[w] = acc;
    __syncthreads();
    if (t == 0)
        atomicAdd(out, (red[0] + red[1] + red[2] + red[3]) * (-1.0f / NPIX));
}

extern "C" void kernel_launch(void* const* d_in, const int* in_sizes, int n_in,
                              void* d_out, int out_size, void* d_ws, size_t ws_size,
                              hipStream_t stream) {
    const float* in = (const float*)d_in[0];
    const float* tg = (const float*)d_in[1];
    float* out = (float*)d_out;

    hipMemsetAsync(out, 0, sizeof(float), stream);
    dim3 grid(N_IMG * BANDS / 4);              // 512 blocks x 4 wave-bands
    cc_loss_kernel<<<grid, 256, 0, stream>>>(in, tg, out);
}

// Round 5
// 106.300 us; speedup vs baseline: 1.4933x; 1.0063x over previous
//
#include <hip/hip_runtime.h>

#define IMG_H 512
#define IMG_W 512
#define N_IMG 32
#define ROWS  8                    // output rows per wave-band
#define BANDS (IMG_H / ROWS)       // 64 bands per image
#define NPIX  (32.0f * 512.0f * 512.0f)

// ---- DPP lane shifts (verified R3/R4): wave_shr:1 / wave_shl:1 with
//      bound_ctrl zero-fill = free image-edge zero padding.
__device__ __forceinline__ float dpp_left(float x) {
    return __int_as_float(__builtin_amdgcn_update_dpp(
        0, __float_as_int(x), 0x138, 0xf, 0xf, true));   // wave_shr:1
}
__device__ __forceinline__ float dpp_right(float x) {
    return __int_as_float(__builtin_amdgcn_update_dpp(
        0, __float_as_int(x), 0x130, 0xf, 0xf, true));   // wave_shl:1
}

// Branch-free loads. EDGE=false: rows guaranteed in range, raw unconditional
// loads (compiler can cluster + pipeline freely). EDGE=true: clamp row and
// wave-uniform select (I=0, T_raw=-1 -> normalizes to 0) -- still no branch.
template<bool EDGE>
__device__ __forceinline__ void load8t(const float* __restrict__ ip,
                                       const float* __restrict__ tp,
                                       int r, int c0, float* I, float* T) {
    const int rc = EDGE ? min(max(r, 0), IMG_H - 1) : r;
    const float* irow = ip + (ptrdiff_t)rc * IMG_W + c0;
    const float* trow = tp + (ptrdiff_t)rc * IMG_W + c0;
    float4 a = *(const float4*)(irow);
    float4 b = *(const float4*)(irow + 4);
    float4 c = *(const float4*)(trow);
    float4 d = *(const float4*)(trow + 4);
    I[0]=a.x; I[1]=a.y; I[2]=a.z; I[3]=a.w;
    I[4]=b.x; I[5]=b.y; I[6]=b.z; I[7]=b.w;
    T[0]=c.x; T[1]=c.y; T[2]=c.z; T[3]=c.w;
    T[4]=d.x; T[5]=d.y; T[6]=d.z; T[7]=d.w;
    if (EDGE) {
        const bool v = (r >= 0) && (r < IMG_H);   // wave-uniform
        #pragma unroll
        for (int j = 0; j < 8; ++j) {
            I[j] = v ? I[j] : 0.0f;
            T[j] = v ? T[j] : -1.0f;
        }
    }
}

__device__ __forceinline__ void slide_lead(const float* LI, const float* LTr,
                                           float* vI, float* vT, float* vII,
                                           float* vTT, float* vIT) {
    #pragma unroll
    for (int j = 0; j < 8; ++j) {
        float li = LI[j];
        float lt = fmaf(LTr[j], 0.5f, 0.5f);
        vI[j]  += li;
        vT[j]  += lt;
        vII[j]  = fmaf(li, li, vII[j]);
        vTT[j]  = fmaf(lt, lt, vTT[j]);
        vIT[j]  = fmaf(li, lt, vIT[j]);
    }
}

__device__ __forceinline__ void slide_full(const float* LI, const float* LTr,
                                           const float* QI, const float* QTr,
                                           float* vI, float* vT, float* vII,
                                           float* vTT, float* vIT) {
    #pragma unroll
    for (int j = 0; j < 8; ++j) {
        float li = LI[j], qi = QI[j];
        float lt = fmaf(LTr[j], 0.5f, 0.5f);
        float qt = fmaf(QTr[j], 0.5f, 0.5f);
        float dI = li - qi, aI = li + qi;
        float dT = lt - qt, aT = lt + qt;
        vI[j]  += dI;
        vT[j]  += dT;
        vII[j]  = fmaf(dI, aI, vII[j]);
        vTT[j]  = fmaf(dT, aT, vTT[j]);
        vIT[j]  = fmaf(li, lt, vIT[j] - qi * qt);
    }
}

__device__ __forceinline__ float cc_of(float sI, float sT, float sII, float sTT, float sIT) {
    const float inv81 = 1.0f / 81.0f;
    float u     = sI * inv81;
    float w     = sT * inv81;
    float cross = fmaf(-u, sT, sIT);
    float iv    = fmaf(-u, sI, sII);
    float tv    = fmaf(-w, sT, sTT);
    float den   = fmaf(tv, iv, 1e-5f);
    return cross * cross * __builtin_amdgcn_rcpf(den);
}

// Horizontal 9-tap sums + cc for 8 own cols; halos via DPP (verified R3/R4).
__device__ __forceinline__ float hphase(const float* vI, const float* vT,
                                        const float* vII, const float* vTT,
                                        const float* vIT) {
    float L0[4],R0[4],L1[4],R1[4],L2[4],R2[4],L3[4],R3[4],L4[4],R4[4];
    #pragma unroll
    for (int k = 0; k < 4; ++k) {
        L0[k] = dpp_left (vI [4+k]);  R0[k] = dpp_right(vI [k]);
        L1[k] = dpp_left (vT [4+k]);  R1[k] = dpp_right(vT [k]);
        L2[k] = dpp_left (vII[4+k]);  R2[k] = dpp_right(vII[k]);
        L3[k] = dpp_left (vTT[4+k]);  R3[k] = dpp_right(vTT[k]);
        L4[k] = dpp_left (vIT[4+k]);  R4[k] = dpp_right(vIT[k]);
    }
    float s0 = ((L0[0]+L0[1])+(L0[2]+L0[3])) + ((vI [0]+vI [1])+(vI [2]+vI [3])) + vI [4];
    float s1 = ((L1[0]+L1[1])+(L1[2]+L1[3])) + ((vT [0]+vT [1])+(vT [2]+vT [3])) + vT [4];
    float s2 = ((L2[0]+L2[1])+(L2[2]+L2[3])) + ((vII[0]+vII[1])+(vII[2]+vII[3])) + vII[4];
    float s3 = ((L3[0]+L3[1])+(L3[2]+L3[3])) + ((vTT[0]+vTT[1])+(vTT[2]+vTT[3])) + vTT[4];
    float s4 = ((L4[0]+L4[1])+(L4[2]+L4[3])) + ((vIT[0]+vIT[1])+(vIT[2]+vIT[3])) + vIT[4];
    float part = cc_of(s0, s1, s2, s3, s4);

    #define HSTEP(a0,a1,a2,a3,a4) \
        s0 += (a0); s1 += (a1); s2 += (a2); s3 += (a3); s4 += (a4); \
        part += cc_of(s0, s1, s2, s3, s4);

    HSTEP(vI[5]-L0[0], vT[5]-L1[0], vII[5]-L2[0], vTT[5]-L3[0], vIT[5]-L4[0])  // j=1
    HSTEP(vI[6]-L0[1], vT[6]-L1[1], vII[6]-L2[1], vTT[6]-L3[1], vIT[6]-L4[1])  // j=2
    HSTEP(vI[7]-L0[2], vT[7]-L1[2], vII[7]-L2[2], vTT[7]-L3[2], vIT[7]-L4[2])  // j=3
    HSTEP(R0[0]-L0[3], R1[0]-L1[3], R2[0]-L2[3], R3[0]-L3[3], R4[0]-L4[3])     // j=4
    HSTEP(R0[1]-vI[0], R1[1]-vT[0], R2[1]-vII[0], R3[1]-vTT[0], R4[1]-vIT[0])  // j=5
    HSTEP(R0[2]-vI[1], R1[2]-vT[1], R2[2]-vII[1], R3[2]-vTT[1], R4[2]-vIT[1])  // j=6
    HSTEP(R0[3]-vI[2], R1[3]-vT[2], R2[3]-vII[2], R3[3]-vTT[2], R4[3]-vIT[2])  // j=7
    #undef HSTEP
    return part;
}

// Whole band, 100% straight-line (no branches anywhere inside).
template<bool EDGE>
__device__ __forceinline__ float band_body(const float* __restrict__ ip,
                                           const float* __restrict__ tp,
                                           int r0, int c0) {
    float vI[8] = {}, vT[8] = {}, vII[8] = {}, vTT[8] = {}, vIT[8] = {};
    float acc = 0.0f;

    float ALI[8], ALT[8], AQI[8], AQT[8];
    float BLI[8], BLT[8], BQI[8], BQT[8];
    float CLI[8], CLT[8], DLI[8], DLT[8];

    // ---- ramp: add window rows r0-4 .. r0+3 (iters 0..7), depth-4 pipeline ----
    load8t<EDGE>(ip, tp, r0 - 4, c0, ALI, ALT);
    load8t<EDGE>(ip, tp, r0 - 3, c0, BLI, BLT);
    load8t<EDGE>(ip, tp, r0 - 2, c0, CLI, CLT);
    load8t<EDGE>(ip, tp, r0 - 1, c0, DLI, DLT);

    slide_lead(ALI, ALT, vI, vT, vII, vTT, vIT);
    load8t<EDGE>(ip, tp, r0 + 0, c0, ALI, ALT);
    slide_lead(BLI, BLT, vI, vT, vII, vTT, vIT);
    load8t<EDGE>(ip, tp, r0 + 1, c0, BLI, BLT);
    slide_lead(CLI, CLT, vI, vT, vII, vTT, vIT);
    load8t<EDGE>(ip, tp, r0 + 2, c0, CLI, CLT);
    slide_lead(DLI, DLT, vI, vT, vII, vTT, vIT);
    load8t<EDGE>(ip, tp, r0 + 3, c0, DLI, DLT);

    slide_lead(ALI, ALT, vI, vT, vII, vTT, vIT);
    load8t<EDGE>(ip, tp, r0 + 4, c0, ALI, ALT);            // lead(iter 8)
    slide_lead(BLI, BLT, vI, vT, vII, vTT, vIT);
    load8t<EDGE>(ip, tp, r0 + 5, c0, BLI, BLT);            // lead(iter 9)
    load8t<EDGE>(ip, tp, r0 - 4, c0, BQI, BQT);            // trail(iter 9)
    slide_lead(CLI, CLT, vI, vT, vII, vTT, vIT);
    slide_lead(DLI, DLT, vI, vT, vII, vTT, vIT);

    // ---- peeled first hot pair (iters 8,9) -> removes the p==0 branch ----
    slide_lead(ALI, ALT, vI, vT, vII, vTT, vIT);           // iter 8 (no trail yet)
    load8t<EDGE>(ip, tp, r0 + 6, c0, ALI, ALT);            // lead(10)
    load8t<EDGE>(ip, tp, r0 - 3, c0, AQI, AQT);            // trail(10)
    acc += hphase(vI, vT, vII, vTT, vIT);

    slide_full(BLI, BLT, BQI, BQT, vI, vT, vII, vTT, vIT); // iter 9
    load8t<EDGE>(ip, tp, r0 + 7, c0, BLI, BLT);            // lead(11)
    load8t<EDGE>(ip, tp, r0 - 2, c0, BQI, BQT);            // trail(11)
    acc += hphase(vI, vT, vII, vTT, vIT);

    // ---- hot: iter pairs (10,11),(12,13),(14,15); body is branch-free ----
    // (p=3 prefetches rows r0+12,r0+13 / r0+3,r0+4 that go unused: harmless,
    //  keeps the body straight-line; interior bands stay in range.)
    #pragma unroll 1
    for (int p = 1; p < 4; ++p) {
        const int k = 8 + 2 * p;
        slide_full(ALI, ALT, AQI, AQT, vI, vT, vII, vTT, vIT);   // iter k
        load8t<EDGE>(ip, tp, r0 + k - 2,  c0, ALI, ALT);         // lead(k+2)
        load8t<EDGE>(ip, tp, r0 + k - 11, c0, AQI, AQT);         // trail(k+2)
        acc += hphase(vI, vT, vII, vTT, vIT);

        slide_full(BLI, BLT, BQI, BQT, vI, vT, vII, vTT, vIT);   // iter k+1
        load8t<EDGE>(ip, tp, r0 + k - 1,  c0, BLI, BLT);         // lead(k+3)
        load8t<EDGE>(ip, tp, r0 + k - 10, c0, BQI, BQT);         // trail(k+3)
        acc += hphase(vI, vT, vII, vTT, vIT);
    }
    return acc;
}

__global__ __launch_bounds__(256)
void cc_loss_kernel(const float* __restrict__ in, const float* __restrict__ tg,
                    float* __restrict__ out) {
    __shared__ float red[4];

    const int t    = threadIdx.x;
    const int w    = t >> 6;
    const int lane = t & 63;

    // XCD-chunked swizzle (R4): each XCD owns 64 consecutive blocks = 4 images.
    const int bid  = blockIdx.x;                       // 0..511
    const int bs   = (bid & 7) * 64 + (bid >> 3);      // bijective (512 % 8 == 0)

    const int gband = bs * 4 + w;              // 0..2047
    const int b     = gband >> 6;              // image (64 bands each)
    const int band  = gband & 63;
    const int r0    = band * ROWS;
    const size_t base = (size_t)b * (IMG_H * IMG_W);
    const float* ip = in + base;
    const float* tp = tg + base;
    const int c0    = lane * 8;                // own image cols c0..c0+7

    // Interior bands (1..62) touch rows r0-4 .. r0+13 = 4..509: no checks.
    float acc;
    if (band >= 1 && band <= 62) acc = band_body<false>(ip, tp, r0, c0);
    else                         acc = band_body<true >(ip, tp, r0, c0);

    // ---- reduction: wave shuffle, one barrier per block, one atomic ----
    #pragma unroll
    for (int off = 32; off > 0; off >>= 1) acc += __shfl_down(acc, off, 64);
    if (lane == 0) red[w] = acc;
    __syncthreads();
    if (t == 0)
        atomicAdd(out, (red[0] + red[1] + red[2] + red[3]) * (-1.0f / NPIX));
}

extern "C" void kernel_launch(void* const* d_in, const int* in_sizes, int n_in,
                              void* d_out, int out_size, void* d_ws, size_t ws_size,
                              hipStream_t stream) {
    const float* in = (const float*)d_in[0];
    const float* tg = (const float*)d_in[1];
    float* out = (float*)d_out;

    hipMemsetAsync(out, 0, sizeof(float), stream);
    dim3 grid(N_IMG * BANDS / 4);              // 512 blocks x 4 wave-bands
    cc_loss_kernel<<<grid, 256, 0, stream>>>(in, tg, out);
}